// Round 2
// baseline (2240.649 us; speedup 1.0000x reference)
//
#include <hip/hip_runtime.h>

typedef __attribute__((ext_vector_type(4))) float f4;
typedef __attribute__((ext_vector_type(8))) __bf16 bf16x8;
typedef __attribute__((ext_vector_type(4))) __bf16 bf16x4;

// dims: E=4 B=8 L=768 C=1024 H=768 Q=144 NH=12 HD=64 O=4096 NL=2 MLP=3072
// stages: Sq={64,48,32} qoff={0,64,112}; T={320,304,288}; loff={0,256,512}

static __device__ inline f4 cvt4(bf16x4 v) {
  return (f4){(float)v[0], (float)v[1], (float)v[2], (float)v[3]};
}

// ---------------------------------------------------------------- gate
__global__ __launch_bounds__(256) void gate_kernel(
    const float* __restrict__ x, const float* __restrict__ lnw,
    const float* __restrict__ lnb, const float* __restrict__ gwm,
    const float* __restrict__ gb, float* __restrict__ out) {
  const long r = blockIdx.x;
  const int tid = threadIdx.x;
  f4 v = *(const f4*)(x + r * 1024 + tid * 4);
  float s1 = v[0] + v[1] + v[2] + v[3];
  float s2 = v[0]*v[0] + v[1]*v[1] + v[2]*v[2] + v[3]*v[3];
#pragma unroll
  for (int off = 32; off; off >>= 1) { s1 += __shfl_down(s1, off); s2 += __shfl_down(s2, off); }
  __shared__ float red[8];
  const int wv = tid >> 6;
  if ((tid & 63) == 0) { red[wv*2] = s1; red[wv*2+1] = s2; }
  __syncthreads();
  const float sum = red[0]+red[2]+red[4]+red[6];
  const float sq  = red[1]+red[3]+red[5]+red[7];
  const float mean = sum * (1.f/1024.f);
  const float var  = sq * (1.f/1024.f) - mean*mean;
  const float rstd = rsqrtf(var + 1e-5f);
  f4 lw = *(const f4*)(lnw + tid*4);
  f4 lb = *(const f4*)(lnb + tid*4);
  f4 acc = {0.f,0.f,0.f,0.f};
#pragma unroll
  for (int i = 0; i < 4; i++) {
    float n = (v[i]-mean)*rstd*lw[i] + lb[i];
    f4 g = *(const f4*)(gwm + (long)(tid*4+i)*4);
    acc += n * g;
  }
#pragma unroll
  for (int off = 32; off; off >>= 1) {
    acc[0] += __shfl_down(acc[0], off); acc[1] += __shfl_down(acc[1], off);
    acc[2] += __shfl_down(acc[2], off); acc[3] += __shfl_down(acc[3], off);
  }
  __shared__ f4 red4[4];
  if ((tid & 63) == 0) red4[wv] = acc;
  __syncthreads();
  if (tid == 0) {
    f4 tot = red4[0] + red4[1] + red4[2] + red4[3];
    float lg[4], mx = -1e30f;
#pragma unroll
    for (int e = 0; e < 4; e++) {
      float tv = tot[e] + gb[e];
      tv = fminf(15.f, fmaxf(-15.f, tv));
      lg[e] = tv; mx = fmaxf(mx, tv);
    }
    float den = 0.f;
#pragma unroll
    for (int e = 0; e < 4; e++) { float ev = __expf(lg[e]-mx); lg[e] = ev; den += ev; }
    const float inv = 1.f/den;
    f4 o;
#pragma unroll
    for (int e = 0; e < 4; e++) o[e] = lg[e]*inv;
    *(f4*)(out + r*4) = o;
  }
}

// ------------------------------------------------- weight transpose+cvt
// src fp32: [z-stride srcZ][K rows][srcLd cols], transposes a K x (32*gridX)
// panel starting at column 0 of src into dst bf16 [z-stride dstZ][N rows][K].
__global__ __launch_bounds__(256) void transpose_cvt(
    const float* __restrict__ src, __bf16* __restrict__ dst,
    int srcLd, int K, long srcZ, long dstZ) {
  __shared__ float tile[32][33];
  const long so = (long)blockIdx.z * srcZ;
  const long dxo = (long)blockIdx.z * dstZ;
  const int n0 = blockIdx.x * 32, k0 = blockIdx.y * 32;
  const int tx = threadIdx.x & 31, ty = threadIdx.x >> 5;
#pragma unroll
  for (int i = ty; i < 32; i += 8)
    tile[i][tx] = src[so + (long)(k0 + i) * srcLd + n0 + tx];
  __syncthreads();
#pragma unroll
  for (int i = ty; i < 32; i += 8)
    dst[dxo + (long)(n0 + i) * K + k0 + tx] = (__bf16)tile[tx][i];
}

// ---------------------------------------------------------------- LN (t rows, fp32 -> bf16)
__global__ __launch_bounds__(256) void ln_rows_kernel(
    const float* __restrict__ in, __bf16* __restrict__ out,
    const float* __restrict__ w, const float* __restrict__ b) {
  const long r = blockIdx.x;
  const int e = (int)(r / 1152);
  const float* src = in + r * 768;
  const int tid = threadIdx.x;
  float v0 = src[tid], v1 = src[tid+256], v2 = src[tid+512];
  float s1 = v0+v1+v2, s2 = v0*v0+v1*v1+v2*v2;
#pragma unroll
  for (int off = 32; off; off >>= 1) { s1 += __shfl_down(s1, off); s2 += __shfl_down(s2, off); }
  __shared__ float red[8];
  const int wv = tid >> 6;
  if ((tid & 63) == 0) { red[wv*2] = s1; red[wv*2+1] = s2; }
  __syncthreads();
  const float sum = red[0]+red[2]+red[4]+red[6];
  const float sq  = red[1]+red[3]+red[5]+red[7];
  const float mean = sum * (1.f/768.f);
  const float var  = sq * (1.f/768.f) - mean*mean;
  const float rstd = rsqrtf(var + 1e-5f);
  const float* wp = w + (long)e * 1536;
  const float* bp = b + (long)e * 1536;
  __bf16* dst = out + r * 768;
  dst[tid]     = (__bf16)((v0-mean)*rstd*wp[tid]     + bp[tid]);
  dst[tid+256] = (__bf16)((v1-mean)*rstd*wp[tid+256] + bp[tid+256]);
  dst[tid+512] = (__bf16)((v2-mean)*rstd*wp[tid+512] + bp[tid+512]);
}

// ---------------------------------------------------------------- LN (kv gather, one stage)
// grid = E*8*T blocks; kv row p: p<Sq -> query token (fp32), else h token (bf16)
__global__ __launch_bounds__(256) void ln_kv_kernel(
    const __bf16* __restrict__ h, const float* __restrict__ query,
    __bf16* __restrict__ out, const float* __restrict__ w, const float* __restrict__ b,
    int T, int Sq, int qoffG, int loff) {
  const long r = blockIdx.x;
  const int e = (int)(r / (8*T));
  const int rem = (int)(r % (8*T));
  const int bb = rem / T;
  const int p = rem % T;
  const int tid = threadIdx.x;
  float v0, v1, v2;
  if (p < Sq) {
    const float* src = query + ((long)e * 144 + qoffG + p) * 768;
    v0 = src[tid]; v1 = src[tid+256]; v2 = src[tid+512];
  } else {
    const __bf16* src = h + (((long)e * 8 + bb) * 768 + loff + (p - Sq)) * 768;
    v0 = (float)src[tid]; v1 = (float)src[tid+256]; v2 = (float)src[tid+512];
  }
  float s1 = v0+v1+v2, s2 = v0*v0+v1*v1+v2*v2;
#pragma unroll
  for (int off = 32; off; off >>= 1) { s1 += __shfl_down(s1, off); s2 += __shfl_down(s2, off); }
  __shared__ float red[8];
  const int wv = tid >> 6;
  if ((tid & 63) == 0) { red[wv*2] = s1; red[wv*2+1] = s2; }
  __syncthreads();
  const float sum = red[0]+red[2]+red[4]+red[6];
  const float sq  = red[1]+red[3]+red[5]+red[7];
  const float mean = sum * (1.f/768.f);
  const float var  = sq * (1.f/768.f) - mean*mean;
  const float rstd = rsqrtf(var + 1e-5f);
  const float* wp = w + (long)e * 1536;
  const float* bp2 = b + (long)e * 1536;
  __bf16* dst = out + r * 768;
  dst[tid]     = (__bf16)((v0-mean)*rstd*wp[tid]     + bp2[tid]);
  dst[tid+256] = (__bf16)((v1-mean)*rstd*wp[tid+256] + bp2[tid+256]);
  dst[tid+512] = (__bf16)((v2-mean)*rstd*wp[tid+512] + bp2[tid+512]);
}

// ---------------------------------------------------------------- t init (broadcast query)
__global__ __launch_bounds__(256) void init_t_kernel(
    const float* __restrict__ query, float* __restrict__ t) {
  const long i4 = ((long)blockIdx.x * 256 + threadIdx.x) * 4;
  const int e = (int)(i4 / 884736);
  const int rq = (int)(i4 % 110592);
  *(f4*)(t + i4) = *(const f4*)(query + (long)e * 110592 + rq);
}

// ---------------------------------------------------------------- MFMA GEMM
// C[M,N] = A[M,K] @ Bt[N,K](bf16), 128x128 tile, BK=32.
// MODE 0: C=acc+bias | 1: gelu(acc+bias) | 2: C(f32)+=vec[n]*(acc+bias)
// MODE 3: C(f32)+=acc+bias | 4: C = vec[m*4+z]*acc + bias (row gate)
struct GemmP {
  const void* A; long sAz; int lda;
  const __bf16* Bt; long sBz; int ldb;
  void* C; long sCz; int ldc;
  const float* bias; long sBiasZ;
  const float* vec; long sVecZ;
  int K;
};

template<int MODE, bool A_BF16, bool C_BF16>
__global__ __launch_bounds__(256) void gemm128(GemmP p) {
  __shared__ __bf16 As[128][40];
  __shared__ __bf16 Bs[128][40];
  const int z = blockIdx.z;
  const __bf16* Bt = p.Bt + (long)z * p.sBz;
  const float* bias = p.bias + (long)z * p.sBiasZ;
  const float* vec = (MODE == 2 || MODE == 4) ? (p.vec + (long)z * p.sVecZ) : nullptr;
  const int m0 = blockIdx.x * 128, n0 = blockIdx.y * 128;
  const int tid = threadIdx.x;
  const int srow = tid >> 1, shalf = (tid & 1) << 4;
  const __bf16* bp = Bt + (long)(n0 + srow) * p.ldb + shalf;
  const float* apf = nullptr; const __bf16* apb = nullptr;
  if (A_BF16) apb = (const __bf16*)p.A + (long)z * p.sAz + (long)(m0 + srow) * p.lda + shalf;
  else        apf = (const float*)p.A + (long)z * p.sAz + (long)(m0 + srow) * p.lda + shalf;
  const int lane = tid & 63;
  const int wm = ((tid >> 6) & 1) * 64, wn = ((tid >> 7) & 1) * 64;
  const int lr = lane & 15, qd = lane >> 4;

  f4 acc[4][4];
#pragma unroll
  for (int i = 0; i < 4; i++)
#pragma unroll
    for (int j = 0; j < 4; j++) acc[i][j] = (f4){0.f, 0.f, 0.f, 0.f};

  for (int k0 = 0; k0 < p.K; k0 += 32) {
    bf16x8 pa0, pa1;
    if (A_BF16) {
      pa0 = *(const bf16x8*)(apb + k0);
      pa1 = *(const bf16x8*)(apb + k0 + 8);
    } else {
      f4 a0 = *(const f4*)(apf + k0);
      f4 a1 = *(const f4*)(apf + k0 + 4);
      f4 a2 = *(const f4*)(apf + k0 + 8);
      f4 a3 = *(const f4*)(apf + k0 + 12);
      pa0[0]=(__bf16)a0[0]; pa0[1]=(__bf16)a0[1]; pa0[2]=(__bf16)a0[2]; pa0[3]=(__bf16)a0[3];
      pa0[4]=(__bf16)a1[0]; pa0[5]=(__bf16)a1[1]; pa0[6]=(__bf16)a1[2]; pa0[7]=(__bf16)a1[3];
      pa1[0]=(__bf16)a2[0]; pa1[1]=(__bf16)a2[1]; pa1[2]=(__bf16)a2[2]; pa1[3]=(__bf16)a2[3];
      pa1[4]=(__bf16)a3[0]; pa1[5]=(__bf16)a3[1]; pa1[6]=(__bf16)a3[2]; pa1[7]=(__bf16)a3[3];
    }
    bf16x8 b0 = *(const bf16x8*)(bp + k0);
    bf16x8 b1 = *(const bf16x8*)(bp + k0 + 8);
    __syncthreads();
    *(bf16x8*)&As[srow][shalf]     = pa0;
    *(bf16x8*)&As[srow][shalf + 8] = pa1;
    *(bf16x8*)&Bs[srow][shalf]     = b0;
    *(bf16x8*)&Bs[srow][shalf + 8] = b1;
    __syncthreads();
    bf16x8 af[4], bfr[4];
#pragma unroll
    for (int i = 0; i < 4; i++) af[i] = *(const bf16x8*)&As[wm + i*16 + lr][qd*8];
#pragma unroll
    for (int j = 0; j < 4; j++) bfr[j] = *(const bf16x8*)&Bs[wn + j*16 + lr][qd*8];
#pragma unroll
    for (int i = 0; i < 4; i++)
#pragma unroll
      for (int j = 0; j < 4; j++)
        acc[i][j] = __builtin_amdgcn_mfma_f32_16x16x32_bf16(af[i], bfr[j], acc[i][j], 0, 0, 0);
  }
  float* Cf = (float*)p.C + (long)z * p.sCz;
  __bf16* Cb = (__bf16*)p.C + (long)z * p.sCz;
#pragma unroll
  for (int i = 0; i < 4; i++) {
    const int rbase = m0 + wm + i*16 + qd*4;
#pragma unroll
    for (int j = 0; j < 4; j++) {
      const int col = n0 + wn + j*16 + lr;
      const float bcol = bias[col];
      f4 v = acc[i][j];
#pragma unroll
      for (int r = 0; r < 4; r++) {
        const long o = (long)(rbase + r) * p.ldc + col;
        const float xx = v[r];
        if (MODE == 0) {
          const float y = xx + bcol;
          if (C_BF16) Cb[o] = (__bf16)y; else Cf[o] = y;
        } else if (MODE == 1) {
          const float y = xx + bcol;
          const float g = 0.5f * y * (1.0f + erff(y * 0.70710678118654752f));
          if (C_BF16) Cb[o] = (__bf16)g; else Cf[o] = g;
        } else if (MODE == 2) {
          Cf[o] += vec[col] * (xx + bcol);
        } else if (MODE == 3) {
          Cf[o] += xx + bcol;
        } else {
          const float y = vec[(long)(rbase + r) * 4 + z] * xx + bcol;
          if (C_BF16) Cb[o] = (__bf16)y; else Cf[o] = y;
        }
      }
    }
  }
}

// ---------------------------------------------------------------- fused attention (one stage)
// grid: x = q-tile (32 rows), y = head, z = e*8+b.  kvh row: [K(768)|V(768)] bf16
__global__ __launch_bounds__(256) void attn_kernel(
    const __bf16* __restrict__ qh, const __bf16* __restrict__ kvh,
    __bf16* __restrict__ att, int T, int Sq, int qoffG) {
  __shared__ float qt[32][68];
  __shared__ float kt[32][68];
  __shared__ float sc[32][321];
  __shared__ float lsum[32];
  const int q0 = blockIdx.x * 32;
  const int nq = (Sq - q0 < 32) ? (Sq - q0) : 32;
  const int hh = blockIdx.y;
  const long eb = blockIdx.z;
  const int tid = threadIdx.x;
  const __bf16* qb = qh + ((long)eb*144 + qoffG + q0)*768 + hh*64;
  const __bf16* kb = kvh + (long)eb*T*1536 + hh*64;
  {
    const int rr = tid >> 3, cc = (tid & 7) * 8;
    f4 z4 = {0.f,0.f,0.f,0.f};
    f4 v0 = z4, v1 = z4;
    if (rr < nq) {
      bf16x8 q8 = *(const bf16x8*)(qb + (long)rr*768 + cc);
      v0 = (f4){(float)q8[0],(float)q8[1],(float)q8[2],(float)q8[3]};
      v1 = (f4){(float)q8[4],(float)q8[5],(float)q8[6],(float)q8[7]};
    }
    *(f4*)&qt[rr][cc] = v0;
    *(f4*)&qt[rr][cc+4] = v1;
  }
  const int tp = (tid & 15) * 2;
  const int qp = (tid >> 4) * 2;
  for (int tt = 0; tt < T; tt += 32) {
    __syncthreads();
    {
      const int rr = tid >> 3, cc = (tid & 7) * 8;
      f4 z4 = {0.f,0.f,0.f,0.f};
      f4 v0 = z4, v1 = z4;
      if (tt + rr < T) {
        bf16x8 k8 = *(const bf16x8*)(kb + (long)(tt+rr)*1536 + cc);
        v0 = (f4){(float)k8[0],(float)k8[1],(float)k8[2],(float)k8[3]};
        v1 = (f4){(float)k8[4],(float)k8[5],(float)k8[6],(float)k8[7]};
      }
      *(f4*)&kt[rr][cc] = v0;
      *(f4*)&kt[rr][cc+4] = v1;
    }
    __syncthreads();
    float d00=0.f, d01=0.f, d10=0.f, d11=0.f;
#pragma unroll
    for (int d = 0; d < 64; d += 4) {
      f4 a0 = *(const f4*)&qt[qp][d];
      f4 a1 = *(const f4*)&qt[qp+1][d];
      f4 k0 = *(const f4*)&kt[tp][d];
      f4 k1 = *(const f4*)&kt[tp+1][d];
      d00 += a0[0]*k0[0]+a0[1]*k0[1]+a0[2]*k0[2]+a0[3]*k0[3];
      d01 += a0[0]*k1[0]+a0[1]*k1[1]+a0[2]*k1[2]+a0[3]*k1[3];
      d10 += a1[0]*k0[0]+a1[1]*k0[1]+a1[2]*k0[2]+a1[3]*k0[3];
      d11 += a1[0]*k1[0]+a1[1]*k1[1]+a1[2]*k1[2]+a1[3]*k1[3];
    }
    const int t0 = tt + tp, t1 = t0 + 1;
    sc[qp][t0]   = (t0 < T) ? d00*0.125f : -1e30f;
    sc[qp][t1]   = (t1 < T) ? d01*0.125f : -1e30f;
    sc[qp+1][t0] = (t0 < T) ? d10*0.125f : -1e30f;
    sc[qp+1][t1] = (t1 < T) ? d11*0.125f : -1e30f;
  }
  __syncthreads();
  const int wv = tid >> 6, lane = tid & 63;
#pragma unroll
  for (int i = 0; i < 8; i++) {
    const int q = wv*8 + i;
    float m = -1e30f;
    for (int t2 = lane; t2 < T; t2 += 64) m = fmaxf(m, sc[q][t2]);
#pragma unroll
    for (int off = 32; off; off >>= 1) m = fmaxf(m, __shfl_down(m, off));
    m = __shfl(m, 0);
    float sum = 0.f;
    for (int t2 = lane; t2 < T; t2 += 64) {
      float ev = __expf(sc[q][t2] - m);
      sc[q][t2] = ev;
      sum += ev;
    }
#pragma unroll
    for (int off = 32; off; off >>= 1) sum += __shfl_down(sum, off);
    if (lane == 0) lsum[q] = sum;
  }
  __syncthreads();
  const int d4 = (tid & 15) * 4;
  const int qi = tid >> 4;
  f4 o0 = {0.f,0.f,0.f,0.f}, o1 = {0.f,0.f,0.f,0.f};
  const __bf16* vb = kb + 768;
#pragma unroll 4
  for (int t2 = 0; t2 < T; t2++) {
    f4 v = cvt4(*(const bf16x4*)(vb + (long)t2*1536 + d4));
    o0 += sc[qi][t2] * v;
    o1 += sc[qi+16][t2] * v;
  }
  o0 *= (1.f / lsum[qi]);
  o1 *= (1.f / lsum[qi+16]);
  __bf16* ob = att + ((long)eb*144 + qoffG + q0)*768 + hh*64 + d4;
  if (qi < nq) {
    bf16x4 w0; w0[0]=(__bf16)o0[0]; w0[1]=(__bf16)o0[1]; w0[2]=(__bf16)o0[2]; w0[3]=(__bf16)o0[3];
    *(bf16x4*)(ob + (long)qi*768) = w0;
  }
  if (qi+16 < nq) {
    bf16x4 w1; w1[0]=(__bf16)o1[0]; w1[1]=(__bf16)o1[1]; w1[2]=(__bf16)o1[2]; w1[3]=(__bf16)o1[3];
    *(bf16x4*)(ob + (long)(qi+16)*768) = w1;
  }
}

// ---------------------------------------------------------------- RMSNorm
__global__ __launch_bounds__(256) void rmsnorm_kernel(
    const float* __restrict__ in, const float* __restrict__ w,
    const float* __restrict__ g, float* __restrict__ out) {
  const long r = blockIdx.x;
  const int tid = threadIdx.x;
  const float* src = in + r*4096;
  f4 vv[4]; float s2 = 0.f;
#pragma unroll
  for (int i = 0; i < 4; i++) {
    vv[i] = *(const f4*)(src + i*1024 + tid*4);
    s2 += vv[i][0]*vv[i][0] + vv[i][1]*vv[i][1] + vv[i][2]*vv[i][2] + vv[i][3]*vv[i][3];
  }
#pragma unroll
  for (int off = 32; off; off >>= 1) s2 += __shfl_down(s2, off);
  __shared__ float red[4];
  if ((tid & 63) == 0) red[tid >> 6] = s2;
  __syncthreads();
  const float ms = (red[0]+red[1]+red[2]+red[3]) * (1.f/4096.f);
  const float scl = rsqrtf(ms + 1e-6f);
#pragma unroll
  for (int i = 0; i < 4; i++) {
    const int o = i*1024 + tid*4;
    f4 wv = *(const f4*)(w + o);
    f4 gv = *(const f4*)(g + o);
    f4 res = vv[i] * scl * wv * gv;
    *(f4*)(out + r*4096 + o) = res;
  }
}

// ================================================================ launch
extern "C" void kernel_launch(void* const* d_in, const int* in_sizes, int n_in,
                              void* d_out, int out_size, void* d_ws, size_t ws_size,
                              hipStream_t stream) {
  const float* x          = (const float*)d_in[0];
  const float* gate_ln_w  = (const float*)d_in[1];
  const float* gate_ln_b  = (const float*)d_in[2];
  const float* gate_w     = (const float*)d_in[3];
  const float* gate_b     = (const float*)d_in[4];
  const float* exp_in_w   = (const float*)d_in[5];
  const float* exp_in_b   = (const float*)d_in[6];
  const float* exp_query  = (const float*)d_in[7];
  const float* ln1_w      = (const float*)d_in[8];
  const float* ln1_b      = (const float*)d_in[9];
  const float* ln1kv_w    = (const float*)d_in[10];
  const float* ln1kv_b    = (const float*)d_in[11];
  const float* ln2_w      = (const float*)d_in[12];
  const float* ln2_b      = (const float*)d_in[13];
  const float* attn_in_w  = (const float*)d_in[14];
  const float* attn_in_b  = (const float*)d_in[15];
  const float* attn_out_w = (const float*)d_in[16];
  const float* attn_out_b = (const float*)d_in[17];
  const float* ls1        = (const float*)d_in[18];
  const float* ls2        = (const float*)d_in[19];
  const float* fc_w       = (const float*)d_in[20];
  const float* fc_b       = (const float*)d_in[21];
  const float* proj_w     = (const float*)d_in[22];
  const float* proj_b     = (const float*)d_in[23];
  const float* out_w      = (const float*)d_in[24];
  const float* out_b      = (const float*)d_in[25];
  const float* rms_w      = (const float*)d_in[26];
  const float* out_gain   = (const float*)d_in[27];
  float* out = (float*)d_out;

  // ---- workspace layout (byte offsets, all 256-aligned), total 132,218,880 B
  char* W = (char*)d_ws;
  float*   gw    = (float*)(W + 0);             //  98,304 B  [6144][4] f32
  float*   t     = (float*)(W + 98304);         //  14,155,776 B [4][1152][768] f32
  __bf16*  qn    = (__bf16*)(W + 14254080);     //   7,077,888 B [4][1152][768] bf16 (alias att)
  __bf16*  qh    = (__bf16*)(W + 21331968);     //   7,077,888 B [4][1152][768] bf16
  __bf16*  kvn   = (__bf16*)(W + 28409856);     //  15,728,640 B [4][8][<=320][768] bf16
  __bf16*  kvh   = (__bf16*)(W + 44138496);     //  31,457,280 B [4][8][<=320][1536] bf16 (alias mid)
  __bf16*  mid   = (__bf16*)(W + 44138496);     //  28,311,552 B [4][1152][3072] bf16
  __bf16*  h     = (__bf16*)(W + 75595776);     //  37,748,736 B [4][8][768][768] bf16
  float*   mixed = (float*)(W + 75595776);      //  18,874,368 B [8][144][4096] f32 (alias h; h dead)
  __bf16*  wbuf  = (__bf16*)(W + 113344512);    //  18,874,368 B weight staging (bf16)
  const size_t NEED = 132218880ull;
  if (ws_size < NEED) return;

  // ---- gating
  gate_kernel<<<6144, 256, 0, stream>>>(x, gate_ln_w, gate_ln_b, gate_w, gate_b, gw);

  // ---- expert input proj: h[e] = gate_e * (x @ exp_in_w[e]) + bias
  transpose_cvt<<<dim3(24,32,4), 256, 0, stream>>>(exp_in_w, wbuf, 768, 1024, 786432, 786432);
  { GemmP p{ x, 0, 1024, wbuf, 786432, 1024, h, 4718592, 768,
             exp_in_b, 768, gw, 0, 1024 };
    gemm128<4,false,true><<<dim3(48,6,4), 256, 0, stream>>>(p); }
  init_t_kernel<<<3456, 256, 0, stream>>>(exp_query, t);

  const int ST[3]  = {320, 304, 288};
  const int SQ[3]  = {64, 48, 32};
  const int QO[3]  = {0, 64, 112};
  const int LO[3]  = {0, 256, 512};
  const int QT[3]  = {2, 2, 1};

  for (int li = 0; li < 2; li++) {
    // attn_in weights for this layer -> wbuf [e][2304][768]
    transpose_cvt<<<dim3(72,24,4), 256, 0, stream>>>(
        attn_in_w + (long)li*768*2304, wbuf, 2304, 768, 3538944, 1769472);
    // q path
    ln_rows_kernel<<<4608, 256, 0, stream>>>(t, qn, ln1_w + li*768, ln1_b + li*768);
    { GemmP p{ qn, 884736, 768, wbuf, 1769472, 768, qh, 884736, 768,
               attn_in_b + li*2304, 4608, nullptr, 0, 768 };
      gemm128<0,true,true><<<dim3(9,6,4), 256, 0, stream>>>(p); }
    // kv path per stage + attention
    for (int s = 0; s < 3; s++) {
      const int T = ST[s];
      ln_kv_kernel<<<32*T, 256, 0, stream>>>(h, exp_query, kvn,
          ln1kv_w + li*768, ln1kv_b + li*768, T, SQ[s], QO[s], LO[s]);
      { GemmP p{ kvn, (long)8*T*768, 768, wbuf + 768*768, 1769472, 768,
                 kvh, (long)8*T*1536, 1536,
                 attn_in_b + li*2304 + 768, 4608, nullptr, 0, 768 };
        gemm128<0,true,true><<<dim3(8*T/128,12,4), 256, 0, stream>>>(p); }
      attn_kernel<<<dim3(QT[s],12,32), 256, 0, stream>>>(qh, kvh, qn /*att*/, T, SQ[s], QO[s]);
    }
    // attn out proj: t += ls1 * (att @ out_w + out_b)
    transpose_cvt<<<dim3(24,24,4), 256, 0, stream>>>(
        attn_out_w + (long)li*589824, wbuf, 768, 768, 1179648, 589824);
    { GemmP p{ qn /*att*/, 884736, 768, wbuf, 589824, 768, t, 884736, 768,
               attn_out_b + li*768, 1536, ls1 + li*768, 1536, 768 };
      gemm128<2,true,false><<<dim3(9,6,4), 256, 0, stream>>>(p); }
    // MLP
    ln_rows_kernel<<<4608, 256, 0, stream>>>(t, qn, ln2_w + li*768, ln2_b + li*768);
    transpose_cvt<<<dim3(96,24,4), 256, 0, stream>>>(
        fc_w + (long)li*768*3072, wbuf, 3072, 768, 4718592, 2359296);
    { GemmP p{ qn, 884736, 768, wbuf, 2359296, 768, mid, 3538944, 3072,
               fc_b + li*3072, 6144, nullptr, 0, 768 };
      gemm128<1,true,true><<<dim3(9,24,4), 256, 0, stream>>>(p); }
    transpose_cvt<<<dim3(24,96,4), 256, 0, stream>>>(
        proj_w + (long)li*3072*768, wbuf, 768, 3072, 4718592, 2359296);
    { GemmP p{ mid, 3538944, 3072, wbuf, 2359296, 3072, t, 884736, 768,
               proj_b + li*768, 1536, ls2 + li*768, 1536, 3072 };
      gemm128<2,true,false><<<dim3(9,6,4), 256, 0, stream>>>(p); }
  }

  // ---- final out proj (accumulated over experts) in two 2048-col chunks
  for (int c = 0; c < 2; c++) {
    transpose_cvt<<<dim3(64,24,4), 256, 0, stream>>>(
        out_w + c*2048, wbuf, 4096, 768, 3145728, 1572864);
    for (int e = 0; e < 4; e++) {
      GemmP p{ t + (long)e*884736, 0, 768, wbuf + (long)e*1572864, 0, 768,
               mixed + c*2048, 0, 4096, out_b + e*4096 + c*2048, 0, nullptr, 0, 768 };
      if (e == 0) gemm128<0,false,false><<<dim3(9,16,1), 256, 0, stream>>>(p);
      else        gemm128<3,false,false><<<dim3(9,16,1), 256, 0, stream>>>(p);
    }
  }
  rmsnorm_kernel<<<1152, 256, 0, stream>>>(mixed, rms_w, out_gain, out);
}

// Round 3
// 1774.451 us; speedup vs baseline: 1.2627x; 1.2627x over previous
//
#include <hip/hip_runtime.h>

typedef __attribute__((ext_vector_type(4))) float f4;
typedef __attribute__((ext_vector_type(8))) __bf16 bf16x8;
typedef __attribute__((ext_vector_type(4))) __bf16 bf16x4;
typedef __attribute__((ext_vector_type(4))) unsigned short u16x4;

// dims: E=4 B=8 L=768 C=1024 H=768 Q=144 NH=12 HD=64 O=4096 NL=2 MLP=3072
// stages: Sq={64,48,32} qoff={0,64,112}; T={320,304,288}; loff={0,256,512}

// ---------------------------------------------------------------- gate
__global__ __launch_bounds__(256) void gate_kernel(
    const float* __restrict__ x, const float* __restrict__ lnw,
    const float* __restrict__ lnb, const float* __restrict__ gwm,
    const float* __restrict__ gb, float* __restrict__ out) {
  const long r = blockIdx.x;
  const int tid = threadIdx.x;
  f4 v = *(const f4*)(x + r * 1024 + tid * 4);
  float s1 = v[0] + v[1] + v[2] + v[3];
  float s2 = v[0]*v[0] + v[1]*v[1] + v[2]*v[2] + v[3]*v[3];
#pragma unroll
  for (int off = 32; off; off >>= 1) { s1 += __shfl_down(s1, off); s2 += __shfl_down(s2, off); }
  __shared__ float red[8];
  const int wv = tid >> 6;
  if ((tid & 63) == 0) { red[wv*2] = s1; red[wv*2+1] = s2; }
  __syncthreads();
  const float sum = red[0]+red[2]+red[4]+red[6];
  const float sq  = red[1]+red[3]+red[5]+red[7];
  const float mean = sum * (1.f/1024.f);
  const float var  = sq * (1.f/1024.f) - mean*mean;
  const float rstd = rsqrtf(var + 1e-5f);
  f4 lw = *(const f4*)(lnw + tid*4);
  f4 lb = *(const f4*)(lnb + tid*4);
  f4 acc = {0.f,0.f,0.f,0.f};
#pragma unroll
  for (int i = 0; i < 4; i++) {
    float n = (v[i]-mean)*rstd*lw[i] + lb[i];
    f4 g = *(const f4*)(gwm + (long)(tid*4+i)*4);
    acc += n * g;
  }
#pragma unroll
  for (int off = 32; off; off >>= 1) {
    acc[0] += __shfl_down(acc[0], off); acc[1] += __shfl_down(acc[1], off);
    acc[2] += __shfl_down(acc[2], off); acc[3] += __shfl_down(acc[3], off);
  }
  __shared__ f4 red4[4];
  if ((tid & 63) == 0) red4[wv] = acc;
  __syncthreads();
  if (tid == 0) {
    f4 tot = red4[0] + red4[1] + red4[2] + red4[3];
    float lg[4], mx = -1e30f;
#pragma unroll
    for (int e = 0; e < 4; e++) {
      float tv = tot[e] + gb[e];
      tv = fminf(15.f, fmaxf(-15.f, tv));
      lg[e] = tv; mx = fmaxf(mx, tv);
    }
    float den = 0.f;
#pragma unroll
    for (int e = 0; e < 4; e++) { float ev = __expf(lg[e]-mx); lg[e] = ev; den += ev; }
    const float inv = 1.f/den;
    f4 o;
#pragma unroll
    for (int e = 0; e < 4; e++) o[e] = lg[e]*inv;
    *(f4*)(out + r*4) = o;
  }
}

// ------------------------------------------------- weight transpose+cvt
__global__ __launch_bounds__(256) void transpose_cvt(
    const float* __restrict__ src, __bf16* __restrict__ dst,
    int srcLd, int K, long srcZ, long dstZ) {
  __shared__ float tile[32][33];
  const long so = (long)blockIdx.z * srcZ;
  const long dxo = (long)blockIdx.z * dstZ;
  const int n0 = blockIdx.x * 32, k0 = blockIdx.y * 32;
  const int tx = threadIdx.x & 31, ty = threadIdx.x >> 5;
#pragma unroll
  for (int i = ty; i < 32; i += 8)
    tile[i][tx] = src[so + (long)(k0 + i) * srcLd + n0 + tx];
  __syncthreads();
#pragma unroll
  for (int i = ty; i < 32; i += 8)
    dst[dxo + (long)(n0 + i) * K + k0 + tx] = (__bf16)tile[tx][i];
}

// ---------------------------------------------------------------- LN (t rows, fp32 -> bf16)
__global__ __launch_bounds__(256) void ln_rows_kernel(
    const float* __restrict__ in, __bf16* __restrict__ out,
    const float* __restrict__ w, const float* __restrict__ b) {
  const long r = blockIdx.x;
  const int e = (int)(r / 1152);
  const float* src = in + r * 768;
  const int tid = threadIdx.x;
  float v0 = src[tid], v1 = src[tid+256], v2 = src[tid+512];
  float s1 = v0+v1+v2, s2 = v0*v0+v1*v1+v2*v2;
#pragma unroll
  for (int off = 32; off; off >>= 1) { s1 += __shfl_down(s1, off); s2 += __shfl_down(s2, off); }
  __shared__ float red[8];
  const int wv = tid >> 6;
  if ((tid & 63) == 0) { red[wv*2] = s1; red[wv*2+1] = s2; }
  __syncthreads();
  const float sum = red[0]+red[2]+red[4]+red[6];
  const float sq  = red[1]+red[3]+red[5]+red[7];
  const float mean = sum * (1.f/768.f);
  const float var  = sq * (1.f/768.f) - mean*mean;
  const float rstd = rsqrtf(var + 1e-5f);
  const float* wp = w + (long)e * 1536;
  const float* bp = b + (long)e * 1536;
  __bf16* dst = out + r * 768;
  dst[tid]     = (__bf16)((v0-mean)*rstd*wp[tid]     + bp[tid]);
  dst[tid+256] = (__bf16)((v1-mean)*rstd*wp[tid+256] + bp[tid+256]);
  dst[tid+512] = (__bf16)((v2-mean)*rstd*wp[tid+512] + bp[tid+512]);
}

// ---------------------------------------------------------------- LN (kv gather, one stage)
__global__ __launch_bounds__(256) void ln_kv_kernel(
    const __bf16* __restrict__ h, const float* __restrict__ query,
    __bf16* __restrict__ out, const float* __restrict__ w, const float* __restrict__ b,
    int T, int Sq, int qoffG, int loff) {
  const long r = blockIdx.x;
  const int e = (int)(r / (8*T));
  const int rem = (int)(r % (8*T));
  const int bb = rem / T;
  const int p = rem % T;
  const int tid = threadIdx.x;
  float v0, v1, v2;
  if (p < Sq) {
    const float* src = query + ((long)e * 144 + qoffG + p) * 768;
    v0 = src[tid]; v1 = src[tid+256]; v2 = src[tid+512];
  } else {
    const __bf16* src = h + (((long)e * 8 + bb) * 768 + loff + (p - Sq)) * 768;
    v0 = (float)src[tid]; v1 = (float)src[tid+256]; v2 = (float)src[tid+512];
  }
  float s1 = v0+v1+v2, s2 = v0*v0+v1*v1+v2*v2;
#pragma unroll
  for (int off = 32; off; off >>= 1) { s1 += __shfl_down(s1, off); s2 += __shfl_down(s2, off); }
  __shared__ float red[8];
  const int wv = tid >> 6;
  if ((tid & 63) == 0) { red[wv*2] = s1; red[wv*2+1] = s2; }
  __syncthreads();
  const float sum = red[0]+red[2]+red[4]+red[6];
  const float sq  = red[1]+red[3]+red[5]+red[7];
  const float mean = sum * (1.f/768.f);
  const float var  = sq * (1.f/768.f) - mean*mean;
  const float rstd = rsqrtf(var + 1e-5f);
  const float* wp = w + (long)e * 1536;
  const float* bp2 = b + (long)e * 1536;
  __bf16* dst = out + r * 768;
  dst[tid]     = (__bf16)((v0-mean)*rstd*wp[tid]     + bp2[tid]);
  dst[tid+256] = (__bf16)((v1-mean)*rstd*wp[tid+256] + bp2[tid+256]);
  dst[tid+512] = (__bf16)((v2-mean)*rstd*wp[tid+512] + bp2[tid+512]);
}

// ---------------------------------------------------------------- t init
__global__ __launch_bounds__(256) void init_t_kernel(
    const float* __restrict__ query, float* __restrict__ t) {
  const long i4 = ((long)blockIdx.x * 256 + threadIdx.x) * 4;
  const int e = (int)(i4 / 884736);
  const int rq = (int)(i4 % 110592);
  *(f4*)(t + i4) = *(const f4*)(query + (long)e * 110592 + rq);
}

// ---------------------------------------------------------------- MFMA GEMM
// MODE 0: C=acc+bias | 1: gelu(acc+bias) | 2: C(f32)+=vec[n]*(acc+bias)
// MODE 3: C(f32)+=acc+bias | 4: C = vec[m*4+z]*acc + bias (row gate)
struct GemmP {
  const void* A; long sAz; int lda;
  const __bf16* Bt; long sBz; int ldb;
  void* C; long sCz; int ldc;
  const float* bias; long sBiasZ;
  const float* vec; long sVecZ;
  int K;
};

template<int MODE, bool A_BF16, bool C_BF16>
__global__ __launch_bounds__(256) void gemm128(GemmP p) {
  __shared__ __bf16 As[128][40];
  __shared__ __bf16 Bs[128][40];
  const int z = blockIdx.z;
  const __bf16* Bt = p.Bt + (long)z * p.sBz;
  const float* bias = p.bias + (long)z * p.sBiasZ;
  const float* vec = (MODE == 2 || MODE == 4) ? (p.vec + (long)z * p.sVecZ) : nullptr;
  const int m0 = blockIdx.x * 128, n0 = blockIdx.y * 128;
  const int tid = threadIdx.x;
  const int srow = tid >> 1, shalf = (tid & 1) << 4;
  const __bf16* bp = Bt + (long)(n0 + srow) * p.ldb + shalf;
  const float* apf = nullptr; const __bf16* apb = nullptr;
  if (A_BF16) apb = (const __bf16*)p.A + (long)z * p.sAz + (long)(m0 + srow) * p.lda + shalf;
  else        apf = (const float*)p.A + (long)z * p.sAz + (long)(m0 + srow) * p.lda + shalf;
  const int lane = tid & 63;
  const int wm = ((tid >> 6) & 1) * 64, wn = ((tid >> 7) & 1) * 64;
  const int lr = lane & 15, qd = lane >> 4;

  f4 acc[4][4];
#pragma unroll
  for (int i = 0; i < 4; i++)
#pragma unroll
    for (int j = 0; j < 4; j++) acc[i][j] = (f4){0.f, 0.f, 0.f, 0.f};

  for (int k0 = 0; k0 < p.K; k0 += 32) {
    bf16x8 pa0, pa1;
    if (A_BF16) {
      pa0 = *(const bf16x8*)(apb + k0);
      pa1 = *(const bf16x8*)(apb + k0 + 8);
    } else {
      f4 a0 = *(const f4*)(apf + k0);
      f4 a1 = *(const f4*)(apf + k0 + 4);
      f4 a2 = *(const f4*)(apf + k0 + 8);
      f4 a3 = *(const f4*)(apf + k0 + 12);
      pa0[0]=(__bf16)a0[0]; pa0[1]=(__bf16)a0[1]; pa0[2]=(__bf16)a0[2]; pa0[3]=(__bf16)a0[3];
      pa0[4]=(__bf16)a1[0]; pa0[5]=(__bf16)a1[1]; pa0[6]=(__bf16)a1[2]; pa0[7]=(__bf16)a1[3];
      pa1[0]=(__bf16)a2[0]; pa1[1]=(__bf16)a2[1]; pa1[2]=(__bf16)a2[2]; pa1[3]=(__bf16)a2[3];
      pa1[4]=(__bf16)a3[0]; pa1[5]=(__bf16)a3[1]; pa1[6]=(__bf16)a3[2]; pa1[7]=(__bf16)a3[3];
    }
    bf16x8 b0 = *(const bf16x8*)(bp + k0);
    bf16x8 b1 = *(const bf16x8*)(bp + k0 + 8);
    __syncthreads();
    *(bf16x8*)&As[srow][shalf]     = pa0;
    *(bf16x8*)&As[srow][shalf + 8] = pa1;
    *(bf16x8*)&Bs[srow][shalf]     = b0;
    *(bf16x8*)&Bs[srow][shalf + 8] = b1;
    __syncthreads();
    bf16x8 af[4], bfr[4];
#pragma unroll
    for (int i = 0; i < 4; i++) af[i] = *(const bf16x8*)&As[wm + i*16 + lr][qd*8];
#pragma unroll
    for (int j = 0; j < 4; j++) bfr[j] = *(const bf16x8*)&Bs[wn + j*16 + lr][qd*8];
#pragma unroll
    for (int i = 0; i < 4; i++)
#pragma unroll
      for (int j = 0; j < 4; j++)
        acc[i][j] = __builtin_amdgcn_mfma_f32_16x16x32_bf16(af[i], bfr[j], acc[i][j], 0, 0, 0);
  }
  float* Cf = (float*)p.C + (long)z * p.sCz;
  __bf16* Cb = (__bf16*)p.C + (long)z * p.sCz;
#pragma unroll
  for (int i = 0; i < 4; i++) {
    const int rbase = m0 + wm + i*16 + qd*4;
#pragma unroll
    for (int j = 0; j < 4; j++) {
      const int col = n0 + wn + j*16 + lr;
      const float bcol = bias[col];
      f4 v = acc[i][j];
#pragma unroll
      for (int r = 0; r < 4; r++) {
        const long o = (long)(rbase + r) * p.ldc + col;
        const float xx = v[r];
        if (MODE == 0) {
          const float y = xx + bcol;
          if (C_BF16) Cb[o] = (__bf16)y; else Cf[o] = y;
        } else if (MODE == 1) {
          const float y = xx + bcol;
          const float g = 0.5f * y * (1.0f + erff(y * 0.70710678118654752f));
          if (C_BF16) Cb[o] = (__bf16)g; else Cf[o] = g;
        } else if (MODE == 2) {
          Cf[o] += vec[col] * (xx + bcol);
        } else if (MODE == 3) {
          Cf[o] += xx + bcol;
        } else {
          const float y = vec[(long)(rbase + r) * 4 + z] * xx + bcol;
          if (C_BF16) Cb[o] = (__bf16)y; else Cf[o] = y;
        }
      }
    }
  }
}

// ---------------------------------------------------------------- MFMA attention
// One block = one (head, e*b). 4 waves. S=QK^T*0.125, softmax, O=PV.
// Q-frag/K-frag loads are direct-from-global 16B/lane (row-major [rows][64]).
// P round-trips through LDS (C/D layout -> A layout). V pair-packed into LDS
// per 32-token chunk so B-frags are single ds_read_b128.
template<int TSQ, int TT>
__global__ __launch_bounds__(256) void attn_mfma_kernel(
    const __bf16* __restrict__ qh, const __bf16* __restrict__ kvh,
    __bf16* __restrict__ att, int qoffG) {
  constexpr int MT = TSQ / 16;        // 4/3/2
  constexpr int NT = TT / 16;         // 20/19/18
  constexpr int NC = (TT + 31) / 32;  // 10/10/9
  constexpr int TC = NC * 32;         // 320/320/288
  constexpr int TPAD = 328;
  __shared__ __bf16 Plds[64 * TPAD];  // 41984 B
  __shared__ unsigned Vt32[64 * 20];  // 5120 B (stride 20 keeps 16B alignment)
  __shared__ float redf[64 * 4];      // 1024 B

  const int hh = blockIdx.x;
  const long eb = blockIdx.y;
  const int tid = threadIdx.x;
  const int w = tid >> 6, lane = tid & 63, lr = lane & 15, qd = lane >> 4;

  const __bf16* qb = qh + ((long)eb * 144 + qoffG) * 768 + hh * 64;
  const __bf16* kb = kvh + (long)eb * TT * 1536 + hh * 64;
  const __bf16* vb = kb + 768;

  // Q fragments (A operand): lane lr = row, k = kc*32 + qd*8 + [0..7]
  bf16x8 qf[MT][2];
#pragma unroll
  for (int mt = 0; mt < MT; mt++)
#pragma unroll
    for (int kc = 0; kc < 2; kc++)
      qf[mt][kc] = *(const bf16x8*)(qb + (long)(mt*16 + lr)*768 + kc*32 + qd*8);

  // S accumulate; wave w owns N-tiles jj = w + 4*j
  f4 sacc[MT][5];
#pragma unroll
  for (int mt = 0; mt < MT; mt++)
#pragma unroll
    for (int j = 0; j < 5; j++) sacc[mt][j] = (f4){0.f,0.f,0.f,0.f};
#pragma unroll
  for (int j = 0; j < 5; j++) {
    const int jj = w + 4*j;
    if (jj < NT) {
      const int t0 = jj * 16;
      bf16x8 kf0 = *(const bf16x8*)(kb + (long)(t0 + lr)*1536 + qd*8);
      bf16x8 kf1 = *(const bf16x8*)(kb + (long)(t0 + lr)*1536 + 32 + qd*8);
#pragma unroll
      for (int mt = 0; mt < MT; mt++) {
        sacc[mt][j] = __builtin_amdgcn_mfma_f32_16x16x32_bf16(qf[mt][0], kf0, sacc[mt][j], 0,0,0);
        sacc[mt][j] = __builtin_amdgcn_mfma_f32_16x16x32_bf16(qf[mt][1], kf1, sacc[mt][j], 0,0,0);
      }
    }
  }

  // row max: per-wave partial, intra-quad reduce, cross-wave via LDS
  float rowmax[MT][4], linv[MT][4], ps[MT][4];
#pragma unroll
  for (int mt = 0; mt < MT; mt++)
#pragma unroll
    for (int r = 0; r < 4; r++) {
      float m = -1e30f;
#pragma unroll
      for (int j = 0; j < 5; j++)
        if (w + 4*j < NT) m = fmaxf(m, sacc[mt][j][r]);
#pragma unroll
      for (int d = 1; d < 16; d <<= 1) m = fmaxf(m, __shfl_xor(m, d));
      rowmax[mt][r] = m;
    }
  if (lr == 0) {
#pragma unroll
    for (int mt = 0; mt < MT; mt++)
#pragma unroll
      for (int r = 0; r < 4; r++)
        redf[(mt*16 + qd*4 + r)*4 + w] = rowmax[mt][r];
  }
  __syncthreads();
#pragma unroll
  for (int mt = 0; mt < MT; mt++)
#pragma unroll
    for (int r = 0; r < 4; r++) {
      f4 v = *(const f4*)&redf[(mt*16 + qd*4 + r)*4];
      rowmax[mt][r] = fmaxf(fmaxf(v[0],v[1]), fmaxf(v[2],v[3])) * 0.125f;
      ps[mt][r] = 0.f;
    }

  // exp, partial sums, write P (bf16) to LDS
#pragma unroll
  for (int j = 0; j < 5; j++) {
    const int jj = w + 4*j;
    if (jj < NT) {
#pragma unroll
      for (int mt = 0; mt < MT; mt++)
#pragma unroll
        for (int r = 0; r < 4; r++) {
          float e = __expf(sacc[mt][j][r]*0.125f - rowmax[mt][r]);
          ps[mt][r] += e;
          Plds[(mt*16 + qd*4 + r)*TPAD + jj*16 + lr] = (__bf16)e;
        }
    }
  }
#pragma unroll
  for (int mt = 0; mt < MT; mt++)
#pragma unroll
    for (int r = 0; r < 4; r++) {
      float s = ps[mt][r];
#pragma unroll
      for (int d = 1; d < 16; d <<= 1) s += __shfl_xor(s, d);
      ps[mt][r] = s;
    }
  __syncthreads();   // max-phase redf reads complete
  if (lr == 0) {
#pragma unroll
    for (int mt = 0; mt < MT; mt++)
#pragma unroll
      for (int r = 0; r < 4; r++)
        redf[(mt*16 + qd*4 + r)*4 + w] = ps[mt][r];
  }
  // zero-pad P columns [TT, TC)
  if (TC > TT) {
    for (int idx = tid; idx < 64*(TC-TT); idx += 256) {
      const int rr = idx / (TC-TT), cc = idx % (TC-TT);
      Plds[rr*TPAD + TT + cc] = (__bf16)0.f;
    }
  }
  __syncthreads();
#pragma unroll
  for (int mt = 0; mt < MT; mt++)
#pragma unroll
    for (int r = 0; r < 4; r++) {
      f4 v = *(const f4*)&redf[(mt*16 + qd*4 + r)*4];
      linv[mt][r] = 1.f / (v[0]+v[1]+v[2]+v[3]);
    }

  // PV: wave w owns dim tile n0 = w*16; K-loop over t chunks of 32
  f4 oacc[MT];
#pragma unroll
  for (int mt = 0; mt < MT; mt++) oacc[mt] = (f4){0.f,0.f,0.f,0.f};
  const int n0 = w * 16;
  for (int c = 0; c < NC; c++) {
    {
      const int tp = tid & 15, dq = tid >> 4;  // tp: t-pair, dq: dim quad (4 dims)
      const int t0v = c*32 + tp*2;
      u16x4 v0 = (u16x4){0,0,0,0}, v1 = (u16x4){0,0,0,0};
      if (t0v < TT)     v0 = *(const u16x4*)(vb + (long)t0v*1536 + dq*4);
      if (t0v + 1 < TT) v1 = *(const u16x4*)(vb + (long)(t0v+1)*1536 + dq*4);
#pragma unroll
      for (int i = 0; i < 4; i++)
        Vt32[(dq*4 + i)*20 + tp] = ((unsigned)v1[i] << 16) | (unsigned)v0[i];
    }
    __syncthreads();
    bf16x8 vf = *(const bf16x8*)&Vt32[(n0 + lr)*20 + qd*4];
#pragma unroll
    for (int mt = 0; mt < MT; mt++) {
      bf16x8 pf = *(const bf16x8*)&Plds[(mt*16 + lr)*TPAD + c*32 + qd*8];
      oacc[mt] = __builtin_amdgcn_mfma_f32_16x16x32_bf16(pf, vf, oacc[mt], 0,0,0);
    }
    __syncthreads();
  }

  // epilogue: row = mt*16 + qd*4 + r, dim = n0 + lr
  __bf16* ob = att + ((long)eb*144 + qoffG)*768 + hh*64 + n0 + lr;
#pragma unroll
  for (int mt = 0; mt < MT; mt++)
#pragma unroll
    for (int r = 0; r < 4; r++) {
      const int row = mt*16 + qd*4 + r;
      ob[(long)row * 768] = (__bf16)(oacc[mt][r] * linv[mt][r]);
    }
}

// ---------------------------------------------------------------- RMSNorm
__global__ __launch_bounds__(256) void rmsnorm_kernel(
    const float* __restrict__ in, const float* __restrict__ w,
    const float* __restrict__ g, float* __restrict__ out) {
  const long r = blockIdx.x;
  const int tid = threadIdx.x;
  const float* src = in + r*4096;
  f4 vv[4]; float s2 = 0.f;
#pragma unroll
  for (int i = 0; i < 4; i++) {
    vv[i] = *(const f4*)(src + i*1024 + tid*4);
    s2 += vv[i][0]*vv[i][0] + vv[i][1]*vv[i][1] + vv[i][2]*vv[i][2] + vv[i][3]*vv[i][3];
  }
#pragma unroll
  for (int off = 32; off; off >>= 1) s2 += __shfl_down(s2, off);
  __shared__ float red[4];
  if ((tid & 63) == 0) red[tid >> 6] = s2;
  __syncthreads();
  const float ms = (red[0]+red[1]+red[2]+red[3]) * (1.f/4096.f);
  const float scl = rsqrtf(ms + 1e-6f);
#pragma unroll
  for (int i = 0; i < 4; i++) {
    const int o = i*1024 + tid*4;
    f4 wv = *(const f4*)(w + o);
    f4 gv = *(const f4*)(g + o);
    f4 res = vv[i] * scl * wv * gv;
    *(f4*)(out + r*4096 + o) = res;
  }
}

// ================================================================ launch
extern "C" void kernel_launch(void* const* d_in, const int* in_sizes, int n_in,
                              void* d_out, int out_size, void* d_ws, size_t ws_size,
                              hipStream_t stream) {
  const float* x          = (const float*)d_in[0];
  const float* gate_ln_w  = (const float*)d_in[1];
  const float* gate_ln_b  = (const float*)d_in[2];
  const float* gate_w     = (const float*)d_in[3];
  const float* gate_b     = (const float*)d_in[4];
  const float* exp_in_w   = (const float*)d_in[5];
  const float* exp_in_b   = (const float*)d_in[6];
  const float* exp_query  = (const float*)d_in[7];
  const float* ln1_w      = (const float*)d_in[8];
  const float* ln1_b      = (const float*)d_in[9];
  const float* ln1kv_w    = (const float*)d_in[10];
  const float* ln1kv_b    = (const float*)d_in[11];
  const float* ln2_w      = (const float*)d_in[12];
  const float* ln2_b      = (const float*)d_in[13];
  const float* attn_in_w  = (const float*)d_in[14];
  const float* attn_in_b  = (const float*)d_in[15];
  const float* attn_out_w = (const float*)d_in[16];
  const float* attn_out_b = (const float*)d_in[17];
  const float* ls1        = (const float*)d_in[18];
  const float* ls2        = (const float*)d_in[19];
  const float* fc_w       = (const float*)d_in[20];
  const float* fc_b       = (const float*)d_in[21];
  const float* proj_w     = (const float*)d_in[22];
  const float* proj_b     = (const float*)d_in[23];
  const float* out_w      = (const float*)d_in[24];
  const float* out_b      = (const float*)d_in[25];
  const float* rms_w      = (const float*)d_in[26];
  const float* out_gain   = (const float*)d_in[27];
  float* out = (float*)d_out;

  // ---- workspace layout (byte offsets), total 132,218,880 B
  char* W = (char*)d_ws;
  float*   gw    = (float*)(W + 0);
  float*   t     = (float*)(W + 98304);
  __bf16*  qn    = (__bf16*)(W + 14254080);     // alias att
  __bf16*  qh    = (__bf16*)(W + 21331968);
  __bf16*  kvn   = (__bf16*)(W + 28409856);
  __bf16*  kvh   = (__bf16*)(W + 44138496);     // alias mid
  __bf16*  mid   = (__bf16*)(W + 44138496);
  __bf16*  h     = (__bf16*)(W + 75595776);
  float*   mixed = (float*)(W + 75595776);      // alias h (h dead by then)
  __bf16*  wbuf  = (__bf16*)(W + 113344512);
  const size_t NEED = 132218880ull;
  if (ws_size < NEED) return;

  // ---- gating
  gate_kernel<<<6144, 256, 0, stream>>>(x, gate_ln_w, gate_ln_b, gate_w, gate_b, gw);

  // ---- expert input proj: h[e] = gate_e * (x @ exp_in_w[e]) + bias
  transpose_cvt<<<dim3(24,32,4), 256, 0, stream>>>(exp_in_w, wbuf, 768, 1024, 786432, 786432);
  { GemmP p{ x, 0, 1024, wbuf, 786432, 1024, h, 4718592, 768,
             exp_in_b, 768, gw, 0, 1024 };
    gemm128<4,false,true><<<dim3(48,6,4), 256, 0, stream>>>(p); }
  init_t_kernel<<<3456, 256, 0, stream>>>(exp_query, t);

  const int ST[3]  = {320, 304, 288};
  const int SQ[3]  = {64, 48, 32};
  const int QO[3]  = {0, 64, 112};
  const int LO[3]  = {0, 256, 512};

  for (int li = 0; li < 2; li++) {
    transpose_cvt<<<dim3(72,24,4), 256, 0, stream>>>(
        attn_in_w + (long)li*768*2304, wbuf, 2304, 768, 3538944, 1769472);
    ln_rows_kernel<<<4608, 256, 0, stream>>>(t, qn, ln1_w + li*768, ln1_b + li*768);
    { GemmP p{ qn, 884736, 768, wbuf, 1769472, 768, qh, 884736, 768,
               attn_in_b + li*2304, 4608, nullptr, 0, 768 };
      gemm128<0,true,true><<<dim3(9,6,4), 256, 0, stream>>>(p); }
    for (int s = 0; s < 3; s++) {
      const int T = ST[s];
      ln_kv_kernel<<<32*T, 256, 0, stream>>>(h, exp_query, kvn,
          ln1kv_w + li*768, ln1kv_b + li*768, T, SQ[s], QO[s], LO[s]);
      { GemmP p{ kvn, (long)8*T*768, 768, wbuf + 768*768, 1769472, 768,
                 kvh, (long)8*T*1536, 1536,
                 attn_in_b + li*2304 + 768, 4608, nullptr, 0, 768 };
        gemm128<0,true,true><<<dim3(8*T/128,12,4), 256, 0, stream>>>(p); }
      if (s == 0)
        attn_mfma_kernel<64,320><<<dim3(12,32), 256, 0, stream>>>(qh, kvh, qn, QO[s]);
      else if (s == 1)
        attn_mfma_kernel<48,304><<<dim3(12,32), 256, 0, stream>>>(qh, kvh, qn, QO[s]);
      else
        attn_mfma_kernel<32,288><<<dim3(12,32), 256, 0, stream>>>(qh, kvh, qn, QO[s]);
    }
    transpose_cvt<<<dim3(24,24,4), 256, 0, stream>>>(
        attn_out_w + (long)li*589824, wbuf, 768, 768, 1179648, 589824);
    { GemmP p{ qn /*att*/, 884736, 768, wbuf, 589824, 768, t, 884736, 768,
               attn_out_b + li*768, 1536, ls1 + li*768, 1536, 768 };
      gemm128<2,true,false><<<dim3(9,6,4), 256, 0, stream>>>(p); }
    ln_rows_kernel<<<4608, 256, 0, stream>>>(t, qn, ln2_w + li*768, ln2_b + li*768);
    transpose_cvt<<<dim3(96,24,4), 256, 0, stream>>>(
        fc_w + (long)li*768*3072, wbuf, 3072, 768, 4718592, 2359296);
    { GemmP p{ qn, 884736, 768, wbuf, 2359296, 768, mid, 3538944, 3072,
               fc_b + li*3072, 6144, nullptr, 0, 768 };
      gemm128<1,true,true><<<dim3(9,24,4), 256, 0, stream>>>(p); }
    transpose_cvt<<<dim3(24,96,4), 256, 0, stream>>>(
        proj_w + (long)li*3072*768, wbuf, 768, 3072, 4718592, 2359296);
    { GemmP p{ mid, 3538944, 3072, wbuf, 2359296, 3072, t, 884736, 768,
               proj_b + li*768, 1536, ls2 + li*768, 1536, 3072 };
      gemm128<2,true,false><<<dim3(9,6,4), 256, 0, stream>>>(p); }
  }

  // ---- final out proj (accumulated over experts) in two 2048-col chunks
  for (int c = 0; c < 2; c++) {
    transpose_cvt<<<dim3(64,24,4), 256, 0, stream>>>(
        out_w + c*2048, wbuf, 4096, 768, 3145728, 1572864);
    for (int e = 0; e < 4; e++) {
      GemmP p{ t + (long)e*884736, 0, 768, wbuf + (long)e*1572864, 0, 768,
               mixed + c*2048, 0, 4096, out_b + e*4096 + c*2048, 0, nullptr, 0, 768 };
      if (e == 0) gemm128<0,false,false><<<dim3(9,16,1), 256, 0, stream>>>(p);
      else        gemm128<3,false,false><<<dim3(9,16,1), 256, 0, stream>>>(p);
    }
  }
  rmsnorm_kernel<<<1152, 256, 0, stream>>>(mixed, rms_w, out_gain, out);
}